// Round 5
// baseline (501.406 us; speedup 1.0000x reference)
//
#include <hip/hip_runtime.h>

#define NN 100000
#define NE 625000
#define HD 128

typedef unsigned int u32;
typedef unsigned short u16;
typedef __bf16 bf16x8 __attribute__((ext_vector_type(8)));
typedef float f32x4 __attribute__((ext_vector_type(4)));
typedef float f32x2 __attribute__((ext_vector_type(2)));

__device__ __forceinline__ u16 f2b(float f) {
  u32 u = __float_as_uint(f);
  u32 r = (u + 0x7FFFu + ((u >> 16) & 1u)) >> 16;
  return (u16)r;
}
__device__ __forceinline__ float b2f(u32 u) { return __uint_as_float(u << 16); }

// ---- weight transpose+cast: Wt[l][which][h][d] = W[l][d][h] as bf16 ----
// which==2 (Wlin): fold residual: Wt = I + Wlin
__global__ void k_prep_w(const float* __restrict__ Wl, const float* __restrict__ Wr,
                         const float* __restrict__ Wlin, u16* __restrict__ Wt) {
  int i = blockIdx.x * blockDim.x + threadIdx.x;
  if (i >= 6 * 16384) return;
  int mat = i >> 14;
  int l = mat / 3, which = mat % 3;
  int rem = i & 16383;
  int hh = rem >> 7, dd = rem & 127;
  const float* src = (which == 0) ? Wl : (which == 1) ? Wr : Wlin;
  float v = src[l * 16384 + dd * 128 + hh];
  if (which == 2 && dd == hh) v += 1.0f;
  Wt[l * (3 * 16384) + which * 16384 + hh * 128 + dd] = f2b(v);
}

__global__ void k_cast_x(const float* __restrict__ x, u16* __restrict__ xb) {
  int i = blockIdx.x * blockDim.x + threadIdx.x;
  if (i >= NN * 32) return;
  float4 v = *(const float4*)(x + i * 4);
  uint2 o;
  o.x = (u32)f2b(v.x) | ((u32)f2b(v.y) << 16);
  o.y = (u32)f2b(v.z) | ((u32)f2b(v.w) << 16);
  *(uint2*)(xb + i * 4) = o;
}

// ---- CSR build ----
__global__ void k_hist(const int* __restrict__ dst, int* __restrict__ deg) {
  int e = blockIdx.x * blockDim.x + threadIdx.x;
  if (e < NE) atomicAdd(&deg[dst[e]], 1);
}

__global__ void k_alloc(const int* __restrict__ deg, int* __restrict__ row_start,
                        int* __restrict__ cursor) {
  int idx = blockIdx.x * blockDim.x + threadIdx.x;
  int lane = threadIdx.x & 63;
  int v = (idx < NN) ? deg[idx] : 0;
  int incl = v;
  #pragma unroll
  for (int off = 1; off < 64; off <<= 1) {
    int t = __shfl_up(incl, off, 64);
    if (lane >= off) incl += t;
  }
  int total = __shfl(incl, 63, 64);
  int base = 0;
  if (lane == 63) base = atomicAdd(cursor, total);
  base = __shfl(base, 63, 64);
  if (idx < NN) row_start[idx] = base + incl - v;
}

__global__ void k_fill(const int* __restrict__ src, const int* __restrict__ dst,
                       const int* __restrict__ row_start, int* __restrict__ cnt,
                       int* __restrict__ ss) {
  int e = blockIdx.x * blockDim.x + threadIdx.x;
  if (e >= NE) return;
  int d = dst[e];
  int p = row_start[d] + atomicAdd(&cnt[d], 1);
  ss[p] = src[e];
}

// ---- M=128 GEMM, B direct-from-global (L1-resident), LDS = lA only ----
// BN+relu on A while staging (bn_sum!=null). Per-column stats of output 0
// (st_sum!=null, only with nB==1): LDS-reduced, 1 atomic/channel/block.
// Epilogue bounces through lA -> coalesced uint4 stores.
// In-place safe (o0 may alias A): block reads only its own rows.
__global__ __launch_bounds__(256) void k_gemm3(
    const u16* __restrict__ A, const u16* __restrict__ Bt0, const u16* __restrict__ Bt1,
    const float* __restrict__ bias0, const float* __restrict__ bias1,
    u16* __restrict__ o0, u16* __restrict__ o1,
    const float* __restrict__ bn_sum, const float* __restrict__ bn_sq,
    const float* __restrict__ bn_g, const float* __restrict__ bn_b,
    float* __restrict__ st_sum, float* __restrict__ st_sq, int nB) {
  __shared__ __align__(16) u16 lA[128 * 132];  // staging layout, then bounce [128][132]
  const int tid = threadIdx.x;
  const int m0 = blockIdx.x * 128;
  const int rr = tid >> 4;
  const int seg = tid & 15;
  const int sK = seg >> 2;
  const int qd = seg & 3;

  float mu[8], sc[8], bb[8];
  if (bn_sum) {
    const float invn = 1.0f / 100000.0f;
    #pragma unroll
    for (int j = 0; j < 8; ++j) {
      int c = seg * 8 + j;
      float m = bn_sum[c] * invn;
      float v = fmaxf(bn_sq[c] * invn - m * m, 0.f);
      mu[j] = m;
      sc[j] = rsqrtf(v + 1e-5f) * bn_g[c];
      bb[j] = bn_b[c];
    }
  }
  // stage A (fragment-major)
  #pragma unroll
  for (int p = 0; p < 8; ++p) {
    int g = m0 + p * 16 + rr;
    int gc = (g < NN) ? g : (NN - 1);
    uint4 v = *(const uint4*)(A + gc * HD + seg * 8);
    if (bn_sum) {
      u32 w[4] = {v.x, v.y, v.z, v.w};
      #pragma unroll
      for (int k = 0; k < 4; ++k) {
        float lo = fmaxf((b2f(w[k] & 0xFFFFu) - mu[2 * k]) * sc[2 * k] + bb[2 * k], 0.f);
        float hi = fmaxf((b2f(w[k] >> 16) - mu[2 * k + 1]) * sc[2 * k + 1] + bb[2 * k + 1], 0.f);
        w[k] = (u32)f2b(lo) | ((u32)f2b(hi) << 16);
      }
      v.x = w[0]; v.y = w[1]; v.z = w[2]; v.w = w[3];
    }
    *(uint4*)(lA + ((p * 4 + sK) * 64 + qd * 16 + rr) * 8) = v;
  }
  __syncthreads();

  const int wv = tid >> 6;
  const int lane = tid & 63;
  const int colt = lane & 15;
  const int rq4 = lane >> 4;       // 0..3
  const int rq = rq4 * 4;
  bf16x8 af[2][4];
  #pragma unroll
  for (int tile = 0; tile < 2; ++tile)
    #pragma unroll
    for (int s = 0; s < 4; ++s)
      af[tile][s] = *(const bf16x8*)(lA + (((wv * 2 + tile) * 4 + s) * 64 + lane) * 8);
  __syncthreads();  // lA free -> bounce buffer

  for (int pass = 0; pass < nB; ++pass) {
    if (pass == 1) __syncthreads();  // pass-0 epilogue done reading lA
    const u16* Bt = (pass == 0) ? Bt0 : Bt1;
    u16* o = (pass == 0) ? o0 : o1;
    const float* bias = (pass == 0) ? bias0 : bias1;
    #pragma unroll
    for (int t = 0; t < 8; ++t) {
      bf16x8 bf[4];
      #pragma unroll
      for (int s = 0; s < 4; ++s)
        bf[s] = *(const bf16x8*)(Bt + (t * 16 + colt) * HD + s * 32 + rq4 * 8);
      const int c = t * 16 + colt;
      const float bs = bias[c];
      #pragma unroll
      for (int tile = 0; tile < 2; ++tile) {
        f32x4 acc = {0.f, 0.f, 0.f, 0.f};
        #pragma unroll
        for (int s = 0; s < 4; ++s)
          acc = __builtin_amdgcn_mfma_f32_16x16x32_bf16(af[tile][s], bf[s], acc, 0, 0, 0);
        #pragma unroll
        for (int r = 0; r < 4; ++r) {
          int lrow = (wv * 2 + tile) * 16 + rq + r;
          lA[lrow * 132 + c] = f2b(acc[r] + bs);
        }
      }
    }
    __syncthreads();  // bounce complete
    // coalesced store + stats partials
    float s8[8], q8[8];
    #pragma unroll
    for (int j = 0; j < 8; ++j) { s8[j] = 0.f; q8[j] = 0.f; }
    const int q = tid >> 4;
    #pragma unroll
    for (int i = 0; i < 8; ++i) {
      int row = i * 16 + q;
      int g = m0 + row;
      if (g < NN) {
        uint4 v = *(const uint4*)(lA + row * 132 + seg * 8);
        *(uint4*)(o + g * HD + seg * 8) = v;
        if (st_sum && pass == 0) {
          u32 w[4] = {v.x, v.y, v.z, v.w};
          #pragma unroll
          for (int k = 0; k < 4; ++k) {
            float lo = b2f(w[k] & 0xFFFFu), hi = b2f(w[k] >> 16);
            s8[2 * k] += lo; q8[2 * k] += lo * lo;
            s8[2 * k + 1] += hi; q8[2 * k + 1] += hi * hi;
          }
        }
      }
    }
    if (st_sum && pass == 0) {
      __syncthreads();  // all bounce reads done -> reuse lA as fp32 reduce buf
      float* red = (float*)lA;
      #pragma unroll
      for (int j = 0; j < 8; ++j) {
        red[q * 128 + seg * 8 + j] = s8[j];
        red[2048 + q * 128 + seg * 8 + j] = q8[j];
      }
      __syncthreads();
      if (tid < 128) {
        float S = 0.f, Q = 0.f;
        #pragma unroll
        for (int u = 0; u < 16; ++u) {
          S += red[u * 128 + tid];
          Q += red[2048 + u * 128 + tid];
        }
        atomicAdd(&st_sum[tid], S);
        atomicAdd(&st_sq[tid], Q);
      }
    }
  }
}

// ---- fused edge phase: dst-per-wave, 4 edges/iter, 1 exp + 11 shuffles ----
__global__ __launch_bounds__(256) void k_edge3(
    const u16* __restrict__ xs_b, const u16* __restrict__ xd_b,
    const int* __restrict__ row_start, const int* __restrict__ deg,
    const int* __restrict__ ss, const float* __restrict__ att,
    const float* __restrict__ cb, u16* __restrict__ out_b) {
  int dv = blockIdx.x * 4 + (threadIdx.x >> 6);
  if (dv >= NN) return;
  int lane = threadIdx.x & 63;
  float2 av = *(const float2*)(att + 2 * lane);
  f32x2 a6 = {0.6f * av.x, 0.6f * av.y};
  f32x2 a4 = {0.4f * av.x, 0.4f * av.y};
  u32 xdp = ((const u32*)xd_b)[dv * 64 + lane];
  f32x2 xd2 = {b2f(xdp & 0xFFFFu), b2f(xdp >> 16)};
  int base = row_start[dv], n = deg[dv];
  const u32* xs32 = (const u32*)xs_b;
  f32x2 acc = {0.f, 0.f};
  float wsum = 0.f;
  for (int e0 = 0; e0 < n; e0 += 4) {
    int idx[4];
    #pragma unroll
    for (int j = 0; j < 4; ++j) {
      int e = e0 + j;
      idx[j] = ss[base + ((e < n) ? e : 0)];
    }
    f32x2 xv[4];
    #pragma unroll
    for (int j = 0; j < 4; ++j) {
      u32 p = xs32[idx[j] * 64 + lane];
      f32x2 t = {b2f(p & 0xFFFFu), b2f(p >> 16)};
      xv[j] = t;
    }
    float q[4];
    #pragma unroll
    for (int j = 0; j < 4; ++j) {
      f32x2 t = xv[j] + xd2;                       // v_pk_add_f32
      f32x2 ab = {__builtin_fabsf(t.x), __builtin_fabsf(t.y)};
      f32x2 qv = a4 * ab + a6 * t;                 // pk_mul + pk_fma
      q[j] = qv.x + qv.y;
    }
    // simultaneous 4-value butterfly: lanes end with full sum of q[lane&3]
    float sA0 = (lane & 1) ? q[1] : q[0];
    float oA0 = (lane & 1) ? q[0] : q[1];
    sA0 += __shfl_xor(oA0, 1, 64);
    float sA1 = (lane & 1) ? q[3] : q[2];
    float oA1 = (lane & 1) ? q[2] : q[3];
    sA1 += __shfl_xor(oA1, 1, 64);
    float sC = (lane & 2) ? sA1 : sA0;
    float oC = (lane & 2) ? sA0 : sA1;
    sC += __shfl_xor(oC, 2, 64);
    sC += __shfl_xor(sC, 4, 64);
    sC += __shfl_xor(sC, 8, 64);
    sC += __shfl_xor(sC, 16, 64);
    sC += __shfl_xor(sC, 32, 64);
    float eE = __expf(sC);
    float w0 = __shfl(eE, 0, 64);
    float w1 = __shfl(eE, 1, 64);
    float w2 = __shfl(eE, 2, 64);
    float w3 = __shfl(eE, 3, 64);
    w1 = (e0 + 1 < n) ? w1 : 0.f;
    w2 = (e0 + 2 < n) ? w2 : 0.f;
    w3 = (e0 + 3 < n) ? w3 : 0.f;
    wsum += (w0 + w1) + (w2 + w3);
    acc += xv[0] * w0;
    acc += xv[1] * w1;
    acc += xv[2] * w2;
    acc += xv[3] * w3;
  }
  float inv = 1.f / (wsum + 1e-16f);
  float2 cbv = *(const float2*)(cb + 2 * lane);
  float o0 = acc.x * inv + cbv.x;
  float o1 = acc.y * inv + cbv.y;
  ((u32*)out_b)[dv * 64 + lane] = (u32)f2b(o0) | ((u32)f2b(o1) << 16);
}

// ---- final BN apply -> fp32 out ----
__global__ void k_bn(const u16* __restrict__ hb, const float* __restrict__ ssum,
                     const float* __restrict__ ssq, const float* __restrict__ gamma,
                     const float* __restrict__ beta, float* __restrict__ fout) {
  int i = blockIdx.x * blockDim.x + threadIdx.x;
  if (i >= NN * 64) return;
  int cp = (i & 63) * 2;
  u32 xp = ((const u32*)hb)[i];
  float v0 = b2f(xp & 0xFFFFu), v1 = b2f(xp >> 16);
  const float invn = 1.0f / 100000.0f;
  float mu0 = ssum[cp] * invn, mu1 = ssum[cp + 1] * invn;
  float va0 = fmaxf(ssq[cp] * invn - mu0 * mu0, 0.f);
  float va1 = fmaxf(ssq[cp + 1] * invn - mu1 * mu1, 0.f);
  float s0 = rsqrtf(va0 + 1e-5f) * gamma[cp];
  float s1 = rsqrtf(va1 + 1e-5f) * gamma[cp + 1];
  float o0 = (v0 - mu0) * s0 + beta[cp];
  float o1 = (v1 - mu1) * s1 + beta[cp + 1];
  int row = i >> 6;
  *(float2*)(fout + row * 128 + cp) = make_float2(o0, o1);
}

extern "C" void kernel_launch(void* const* d_in, const int* in_sizes, int n_in,
                              void* d_out, int out_size, void* d_ws, size_t ws_size,
                              hipStream_t stream) {
  const float* x    = (const float*)d_in[0];
  const int*   ei   = (const int*)d_in[1];
  const float* Wl   = (const float*)d_in[2];
  const float* bl   = (const float*)d_in[3];
  const float* Wr   = (const float*)d_in[4];
  const float* br   = (const float*)d_in[5];
  const float* att  = (const float*)d_in[6];
  const float* cb   = (const float*)d_in[7];
  const float* Wlin = (const float*)d_in[8];
  const float* blin = (const float*)d_in[9];
  const float* gm   = (const float*)d_in[10];
  const float* bt   = (const float*)d_in[11];
  const int* esrc = ei;
  const int* edst = ei + NE;

  // ws layout
  u16* xb    = (u16*)d_ws;            // N*128 bf16  (layer0 input)
  u16* xs_b  = xb + NN * HD;
  u16* xd_b  = xs_b + NN * HD;
  u16* out_b = xd_b + NN * HD;        // conv out; lin GEMM runs in-place here
  u16* Wt    = out_b + NN * HD;       // 6*16384 bf16
  int* deg       = (int*)(Wt + 6 * 16384);
  int* cnt       = deg + NN;
  int* cursor    = cnt + NN;
  int* row_start = cursor + 1;
  int* srcs      = row_start + NN;    // E ints
  float* ssum0   = (float*)(srcs + NE);
  float* ssq0    = ssum0 + 128;
  float* ssum1   = ssq0 + 128;
  float* ssq1    = ssum1 + 128;

  hipMemsetAsync(deg, 0, (size_t)(2 * NN + 1) * 4, stream);
  hipMemsetAsync(ssum0, 0, 4 * 128 * 4, stream);
  k_prep_w<<<(6 * 16384 + 255) / 256, 256, 0, stream>>>(Wl, Wr, Wlin, Wt);
  k_cast_x<<<(NN * 32 + 255) / 256, 256, 0, stream>>>(x, xb);
  k_hist<<<(NE + 255) / 256, 256, 0, stream>>>(edst, deg);
  k_alloc<<<(NN + 255) / 256, 256, 0, stream>>>(deg, row_start, cursor);
  k_fill<<<(NE + 255) / 256, 256, 0, stream>>>(esrc, edst, row_start, cnt, srcs);

  const int gg = (NN + 127) / 128;
  const u16* wt0_l = Wt;             const u16* wt0_r = Wt + 16384;     const u16* wt0_lin = Wt + 2 * 16384;
  const u16* wt1_l = Wt + 3 * 16384; const u16* wt1_r = Wt + 4 * 16384; const u16* wt1_lin = Wt + 5 * 16384;

  // ---- layer 0 ----
  k_gemm3<<<gg, 256, 0, stream>>>(xb, wt0_l, wt0_r, bl, br, xs_b, xd_b,
                                  nullptr, nullptr, nullptr, nullptr,
                                  nullptr, nullptr, 2);
  k_edge3<<<(NN + 3) / 4, 256, 0, stream>>>(xs_b, xd_b, row_start, deg, srcs,
                                            att, cb, out_b);
  k_gemm3<<<gg, 256, 0, stream>>>(out_b, wt0_lin, nullptr, blin, nullptr,
                                  out_b, nullptr,
                                  nullptr, nullptr, nullptr, nullptr,
                                  ssum0, ssq0, 1);
  // ---- layer 1 (BN+relu of h0 fused into A staging) ----
  k_gemm3<<<gg, 256, 0, stream>>>(out_b, wt1_l, wt1_r, bl + 128, br + 128,
                                  xs_b, xd_b,
                                  ssum0, ssq0, gm, bt,
                                  nullptr, nullptr, 2);
  k_edge3<<<(NN + 3) / 4, 256, 0, stream>>>(xs_b, xd_b, row_start, deg, srcs,
                                            att + 128, cb + 128, out_b);
  k_gemm3<<<gg, 256, 0, stream>>>(out_b, wt1_lin, nullptr, blin + 128, nullptr,
                                  out_b, nullptr,
                                  nullptr, nullptr, nullptr, nullptr,
                                  ssum1, ssq1, 1);
  k_bn<<<(NN * 64 + 255) / 256, 256, 0, stream>>>(out_b, ssum1, ssq1,
                                                  gm + 128, bt + 128, (float*)d_out);
}

// Round 6
// 465.564 us; speedup vs baseline: 1.0770x; 1.0770x over previous
//
#include <hip/hip_runtime.h>

#define NN 100000
#define NE 625000
#define HD 128

typedef unsigned int u32;
typedef unsigned short u16;
typedef __bf16 bf16x8 __attribute__((ext_vector_type(8)));
typedef float f32x4 __attribute__((ext_vector_type(4)));
typedef float f32x2 __attribute__((ext_vector_type(2)));

__device__ __forceinline__ u16 f2b(float f) {
  u32 u = __float_as_uint(f);
  u32 r = (u + 0x7FFFu + ((u >> 16) & 1u)) >> 16;
  return (u16)r;
}
__device__ __forceinline__ float b2f(u32 u) { return __uint_as_float(u << 16); }

// ---- weight transpose+cast: Wt[l][which][h][d] = W[l][d][h] as bf16 ----
// which==2 (Wlin): fold residual: Wt = I + Wlin
__global__ void k_prep_w(const float* __restrict__ Wl, const float* __restrict__ Wr,
                         const float* __restrict__ Wlin, u16* __restrict__ Wt) {
  int i = blockIdx.x * blockDim.x + threadIdx.x;
  if (i >= 6 * 16384) return;
  int mat = i >> 14;
  int l = mat / 3, which = mat % 3;
  int rem = i & 16383;
  int hh = rem >> 7, dd = rem & 127;
  const float* src = (which == 0) ? Wl : (which == 1) ? Wr : Wlin;
  float v = src[l * 16384 + dd * 128 + hh];
  if (which == 2 && dd == hh) v += 1.0f;
  Wt[l * (3 * 16384) + which * 16384 + hh * 128 + dd] = f2b(v);
}

__global__ void k_cast_x(const float* __restrict__ x, u16* __restrict__ xb) {
  int i = blockIdx.x * blockDim.x + threadIdx.x;
  if (i >= NN * 32) return;
  float4 v = *(const float4*)(x + i * 4);
  uint2 o;
  o.x = (u32)f2b(v.x) | ((u32)f2b(v.y) << 16);
  o.y = (u32)f2b(v.z) | ((u32)f2b(v.w) << 16);
  *(uint2*)(xb + i * 4) = o;
}

// ---- CSR build ----
__global__ void k_hist(const int* __restrict__ dst, int* __restrict__ deg) {
  int e = blockIdx.x * blockDim.x + threadIdx.x;
  if (e < NE) atomicAdd(&deg[dst[e]], 1);
}

__global__ void k_alloc(const int* __restrict__ deg, int* __restrict__ row_start,
                        int* __restrict__ cursor) {
  int idx = blockIdx.x * blockDim.x + threadIdx.x;
  int lane = threadIdx.x & 63;
  int v = (idx < NN) ? deg[idx] : 0;
  int incl = v;
  #pragma unroll
  for (int off = 1; off < 64; off <<= 1) {
    int t = __shfl_up(incl, off, 64);
    if (lane >= off) incl += t;
  }
  int total = __shfl(incl, 63, 64);
  int base = 0;
  if (lane == 63) base = atomicAdd(cursor, total);
  base = __shfl(base, 63, 64);
  if (idx < NN) row_start[idx] = base + incl - v;
}

__global__ void k_fill(const int* __restrict__ src, const int* __restrict__ dst,
                       const int* __restrict__ row_start, int* __restrict__ cnt,
                       int* __restrict__ ss) {
  int e = blockIdx.x * blockDim.x + threadIdx.x;
  if (e >= NE) return;
  int d = dst[e];
  int p = row_start[d] + atomicAdd(&cnt[d], 1);
  ss[p] = src[e];
}

// ---- M=128 GEMM: row-major stride-136 LDS (conflict-free), half-B staging
// (52KB LDS -> 3 blocks/CU). BN+relu on A while staging (bn_sum!=null).
// Per-column stats of output 0 (st_sum!=null, nB==1): LDS-reduced, 1
// atomic/channel/block. Epilogue bounces through lA -> coalesced uint4.
// In-place safe (o0 may alias A): block reads only its own rows.
__global__ __launch_bounds__(256) void k_gemm4(
    const u16* __restrict__ A, const u16* __restrict__ Bt0, const u16* __restrict__ Bt1,
    const float* __restrict__ bias0, const float* __restrict__ bias1,
    u16* __restrict__ o0, u16* __restrict__ o1,
    const float* __restrict__ bn_sum, const float* __restrict__ bn_sq,
    const float* __restrict__ bn_g, const float* __restrict__ bn_b,
    float* __restrict__ st_sum, float* __restrict__ st_sq, int nB) {
  __shared__ __align__(16) u16 lA[128 * 136];  // A staging, then output bounce
  __shared__ __align__(16) u16 lB[64 * 136];   // B half-staging; stats reduce buf
  const int tid = threadIdx.x;
  const int m0 = blockIdx.x * 128;
  const int rr = tid >> 4;      // 0..15 (row within 16-row group)
  const int seg = tid & 15;     // 16B col chunk

  float mu[8], sc[8], bb[8];
  if (bn_sum) {
    const float invn = 1.0f / 100000.0f;
    #pragma unroll
    for (int j = 0; j < 8; ++j) {
      int c = seg * 8 + j;
      float m = bn_sum[c] * invn;
      float v = fmaxf(bn_sq[c] * invn - m * m, 0.f);
      mu[j] = m;
      sc[j] = rsqrtf(v + 1e-5f) * bn_g[c];
      bb[j] = bn_b[c];
    }
  }
  // stage A rows m0..m0+127, row-major stride 136
  #pragma unroll
  for (int p = 0; p < 8; ++p) {
    int row = p * 16 + rr;
    int g = m0 + row;
    int gc = (g < NN) ? g : (NN - 1);
    uint4 v = *(const uint4*)(A + gc * HD + seg * 8);
    if (bn_sum) {
      u32 w[4] = {v.x, v.y, v.z, v.w};
      #pragma unroll
      for (int k = 0; k < 4; ++k) {
        float lo = fmaxf((b2f(w[k] & 0xFFFFu) - mu[2 * k]) * sc[2 * k] + bb[2 * k], 0.f);
        float hi = fmaxf((b2f(w[k] >> 16) - mu[2 * k + 1]) * sc[2 * k + 1] + bb[2 * k + 1], 0.f);
        w[k] = (u32)f2b(lo) | ((u32)f2b(hi) << 16);
      }
      v.x = w[0]; v.y = w[1]; v.z = w[2]; v.w = w[3];
    }
    *(uint4*)(lA + row * 136 + seg * 8) = v;
  }
  // stage B(pass0, half0): Bt0 rows 0..63
  #pragma unroll
  for (int p = 0; p < 4; ++p) {
    int n = p * 16 + rr;
    uint4 v = *(const uint4*)(Bt0 + n * HD + seg * 8);
    *(uint4*)(lB + n * 136 + seg * 8) = v;
  }
  __syncthreads();

  const int wv = tid >> 6;
  const int lane = tid & 63;
  const int colt = lane & 15;      // m (or n) within 16
  const int kq = lane >> 4;        // k quad 0..3
  const int rq = kq * 4;           // C-layout row group
  bf16x8 af[2][4];
  #pragma unroll
  for (int tile = 0; tile < 2; ++tile)
    #pragma unroll
    for (int s = 0; s < 4; ++s)
      af[tile][s] = *(const bf16x8*)(lA + ((wv * 2 + tile) * 16 + colt) * 136 + s * 32 + kq * 8);
  // NOTE: no sync needed before bounce writes — each wave bounces only into
  // its own 32 rows of lA, which only itself frag-read.

  for (int pass = 0; pass < nB; ++pass) {
    const u16* Bt = pass ? Bt1 : Bt0;
    u16* o = pass ? o1 : o0;
    const float* bias = pass ? bias1 : bias0;
    if (pass == 1) {
      __syncthreads();  // pass-0 epilogue done with lA; lB free
      #pragma unroll
      for (int p = 0; p < 4; ++p) {
        int n = p * 16 + rr;
        uint4 v = *(const uint4*)(Bt + n * HD + seg * 8);
        *(uint4*)(lB + n * 136 + seg * 8) = v;
      }
      __syncthreads();
    }
    #pragma unroll
    for (int half = 0; half < 2; ++half) {
      if (half == 1) {
        __syncthreads();  // all waves done reading lB half0
        #pragma unroll
        for (int p = 0; p < 4; ++p) {
          int n = p * 16 + rr;
          uint4 v = *(const uint4*)(Bt + (64 + n) * HD + seg * 8);
          *(uint4*)(lB + n * 136 + seg * 8) = v;
        }
        __syncthreads();
      }
      #pragma unroll
      for (int tt = 0; tt < 4; ++tt) {
        int t = half * 4 + tt;
        bf16x8 bf[4];
        #pragma unroll
        for (int s = 0; s < 4; ++s)
          bf[s] = *(const bf16x8*)(lB + (tt * 16 + colt) * 136 + s * 32 + kq * 8);
        const int c = t * 16 + colt;
        const float bs = bias[c];
        #pragma unroll
        for (int tile = 0; tile < 2; ++tile) {
          f32x4 acc = {0.f, 0.f, 0.f, 0.f};
          #pragma unroll
          for (int s = 0; s < 4; ++s)
            acc = __builtin_amdgcn_mfma_f32_16x16x32_bf16(af[tile][s], bf[s], acc, 0, 0, 0);
          #pragma unroll
          for (int r = 0; r < 4; ++r)
            lA[((wv * 2 + tile) * 16 + rq + r) * 136 + c] = f2b(acc[r] + bs);
        }
      }
    }
    __syncthreads();  // bounce complete (cross-wave) + lB reads done
    // coalesced store + stats partials
    float s8[8], q8[8];
    #pragma unroll
    for (int j = 0; j < 8; ++j) { s8[j] = 0.f; q8[j] = 0.f; }
    #pragma unroll
    for (int i = 0; i < 8; ++i) {
      int row = i * 16 + rr;
      int g = m0 + row;
      if (g < NN) {
        uint4 v = *(const uint4*)(lA + row * 136 + seg * 8);
        *(uint4*)(o + g * HD + seg * 8) = v;
        if (st_sum && pass == 0) {
          u32 w[4] = {v.x, v.y, v.z, v.w};
          #pragma unroll
          for (int k = 0; k < 4; ++k) {
            float lo = b2f(w[k] & 0xFFFFu), hi = b2f(w[k] >> 16);
            s8[2 * k] += lo; q8[2 * k] += lo * lo;
            s8[2 * k + 1] += hi; q8[2 * k + 1] += hi * hi;
          }
        }
      }
    }
    if (st_sum && pass == 0) {
      __syncthreads();  // lB free (t-loop done) -> fp32 reduce buffer (16KB)
      float* red = (float*)lB;
      #pragma unroll
      for (int j = 0; j < 8; ++j) {
        red[rr * 128 + seg * 8 + j] = s8[j];
        red[2048 + rr * 128 + seg * 8 + j] = q8[j];
      }
      __syncthreads();
      if (tid < 128) {
        float S = 0.f, Q = 0.f;
        #pragma unroll
        for (int u = 0; u < 16; ++u) {
          S += red[u * 128 + tid];
          Q += red[2048 + u * 128 + tid];
        }
        atomicAdd(&st_sum[tid], S);
        atomicAdd(&st_sq[tid], Q);
      }
    }
  }
}

// ---- fused edge phase: dst-per-wave, 4 edges/iter, 1 exp2 + 11 shuffles ----
__global__ __launch_bounds__(256) void k_edge3(
    const u16* __restrict__ xs_b, const u16* __restrict__ xd_b,
    const int* __restrict__ row_start, const int* __restrict__ deg,
    const int* __restrict__ ss, const float* __restrict__ att,
    const float* __restrict__ cb, u16* __restrict__ out_b) {
  int dv = blockIdx.x * 4 + (threadIdx.x >> 6);
  if (dv >= NN) return;
  int lane = threadIdx.x & 63;
  float2 av = *(const float2*)(att + 2 * lane);
  const float L2E = 1.4426950408889634f;      // fold log2(e): exp(q)=exp2(q*L2E)
  f32x2 a6 = {L2E * 0.6f * av.x, L2E * 0.6f * av.y};
  f32x2 a4 = {L2E * 0.4f * av.x, L2E * 0.4f * av.y};
  u32 xdp = ((const u32*)xd_b)[dv * 64 + lane];
  f32x2 xd2 = {b2f(xdp & 0xFFFFu), b2f(xdp >> 16)};
  int base = row_start[dv], n = deg[dv];
  const u32* xs32 = (const u32*)xs_b;
  f32x2 acc = {0.f, 0.f};
  float wsum = 0.f;
  for (int e0 = 0; e0 < n; e0 += 4) {
    int idx[4];
    #pragma unroll
    for (int j = 0; j < 4; ++j) {
      int e = e0 + j;
      idx[j] = ss[base + ((e < n) ? e : 0)];
    }
    f32x2 xv[4];
    #pragma unroll
    for (int j = 0; j < 4; ++j) {
      u32 p = xs32[idx[j] * 64 + lane];
      f32x2 t = {b2f(p & 0xFFFFu), b2f(p >> 16)};
      xv[j] = t;
    }
    float q[4];
    #pragma unroll
    for (int j = 0; j < 4; ++j) {
      f32x2 t = xv[j] + xd2;
      f32x2 ab = {__builtin_fabsf(t.x), __builtin_fabsf(t.y)};
      f32x2 qv = a4 * ab + a6 * t;               // lrelu*att*log2e
      q[j] = qv.x + qv.y;
    }
    // simultaneous 4-value butterfly: lanes end with full sum of q[lane&3]
    float sA0 = (lane & 1) ? q[1] : q[0];
    float oA0 = (lane & 1) ? q[0] : q[1];
    sA0 += __shfl_xor(oA0, 1, 64);
    float sA1 = (lane & 1) ? q[3] : q[2];
    float oA1 = (lane & 1) ? q[2] : q[3];
    sA1 += __shfl_xor(oA1, 1, 64);
    float sC = (lane & 2) ? sA1 : sA0;
    float oC = (lane & 2) ? sA0 : sA1;
    sC += __shfl_xor(oC, 2, 64);
    sC += __shfl_xor(sC, 4, 64);
    sC += __shfl_xor(sC, 8, 64);
    sC += __shfl_xor(sC, 16, 64);
    sC += __shfl_xor(sC, 32, 64);
    float eE = exp2f(sC);
    float w0 = __shfl(eE, 0, 64);
    float w1 = __shfl(eE, 1, 64);
    float w2 = __shfl(eE, 2, 64);
    float w3 = __shfl(eE, 3, 64);
    w1 = (e0 + 1 < n) ? w1 : 0.f;
    w2 = (e0 + 2 < n) ? w2 : 0.f;
    w3 = (e0 + 3 < n) ? w3 : 0.f;
    wsum += (w0 + w1) + (w2 + w3);
    acc += xv[0] * w0;
    acc += xv[1] * w1;
    acc += xv[2] * w2;
    acc += xv[3] * w3;
  }
  float inv = 1.f / (wsum + 1e-16f);
  float2 cbv = *(const float2*)(cb + 2 * lane);
  float o0 = acc.x * inv + cbv.x;
  float o1 = acc.y * inv + cbv.y;
  ((u32*)out_b)[dv * 64 + lane] = (u32)f2b(o0) | ((u32)f2b(o1) << 16);
}

// ---- final BN apply -> fp32 out ----
__global__ void k_bn(const u16* __restrict__ hb, const float* __restrict__ ssum,
                     const float* __restrict__ ssq, const float* __restrict__ gamma,
                     const float* __restrict__ beta, float* __restrict__ fout) {
  int i = blockIdx.x * blockDim.x + threadIdx.x;
  if (i >= NN * 64) return;
  int cp = (i & 63) * 2;
  u32 xp = ((const u32*)hb)[i];
  float v0 = b2f(xp & 0xFFFFu), v1 = b2f(xp >> 16);
  const float invn = 1.0f / 100000.0f;
  float mu0 = ssum[cp] * invn, mu1 = ssum[cp + 1] * invn;
  float va0 = fmaxf(ssq[cp] * invn - mu0 * mu0, 0.f);
  float va1 = fmaxf(ssq[cp + 1] * invn - mu1 * mu1, 0.f);
  float s0 = rsqrtf(va0 + 1e-5f) * gamma[cp];
  float s1 = rsqrtf(va1 + 1e-5f) * gamma[cp + 1];
  float o0 = (v0 - mu0) * s0 + beta[cp];
  float o1 = (v1 - mu1) * s1 + beta[cp + 1];
  int row = i >> 6;
  *(float2*)(fout + row * 128 + cp) = make_float2(o0, o1);
}

extern "C" void kernel_launch(void* const* d_in, const int* in_sizes, int n_in,
                              void* d_out, int out_size, void* d_ws, size_t ws_size,
                              hipStream_t stream) {
  const float* x    = (const float*)d_in[0];
  const int*   ei   = (const int*)d_in[1];
  const float* Wl   = (const float*)d_in[2];
  const float* bl   = (const float*)d_in[3];
  const float* Wr   = (const float*)d_in[4];
  const float* br   = (const float*)d_in[5];
  const float* att  = (const float*)d_in[6];
  const float* cb   = (const float*)d_in[7];
  const float* Wlin = (const float*)d_in[8];
  const float* blin = (const float*)d_in[9];
  const float* gm   = (const float*)d_in[10];
  const float* bt   = (const float*)d_in[11];
  const int* esrc = ei;
  const int* edst = ei + NE;

  // ws layout
  u16* xb    = (u16*)d_ws;            // N*128 bf16  (layer0 input)
  u16* xs_b  = xb + NN * HD;
  u16* xd_b  = xs_b + NN * HD;
  u16* out_b = xd_b + NN * HD;        // conv out; lin GEMM runs in-place here
  u16* Wt    = out_b + NN * HD;       // 6*16384 bf16
  int* deg       = (int*)(Wt + 6 * 16384);
  int* cnt       = deg + NN;
  int* cursor    = cnt + NN;
  int* row_start = cursor + 1;
  int* srcs      = row_start + NN;    // E ints
  float* ssum0   = (float*)(srcs + NE);
  float* ssq0    = ssum0 + 128;
  float* ssum1   = ssq0 + 128;
  float* ssq1    = ssum1 + 128;

  hipMemsetAsync(deg, 0, (size_t)(2 * NN + 1) * 4, stream);
  hipMemsetAsync(ssum0, 0, 4 * 128 * 4, stream);
  k_prep_w<<<(6 * 16384 + 255) / 256, 256, 0, stream>>>(Wl, Wr, Wlin, Wt);
  k_cast_x<<<(NN * 32 + 255) / 256, 256, 0, stream>>>(x, xb);
  k_hist<<<(NE + 255) / 256, 256, 0, stream>>>(edst, deg);
  k_alloc<<<(NN + 255) / 256, 256, 0, stream>>>(deg, row_start, cursor);
  k_fill<<<(NE + 255) / 256, 256, 0, stream>>>(esrc, edst, row_start, cnt, srcs);

  const int gg = (NN + 127) / 128;
  const u16* wt0_l = Wt;             const u16* wt0_r = Wt + 16384;     const u16* wt0_lin = Wt + 2 * 16384;
  const u16* wt1_l = Wt + 3 * 16384; const u16* wt1_r = Wt + 4 * 16384; const u16* wt1_lin = Wt + 5 * 16384;

  // ---- layer 0 ----
  k_gemm4<<<gg, 256, 0, stream>>>(xb, wt0_l, wt0_r, bl, br, xs_b, xd_b,
                                  nullptr, nullptr, nullptr, nullptr,
                                  nullptr, nullptr, 2);
  k_edge3<<<(NN + 3) / 4, 256, 0, stream>>>(xs_b, xd_b, row_start, deg, srcs,
                                            att, cb, out_b);
  k_gemm4<<<gg, 256, 0, stream>>>(out_b, wt0_lin, nullptr, blin, nullptr,
                                  out_b, nullptr,
                                  nullptr, nullptr, nullptr, nullptr,
                                  ssum0, ssq0, 1);
  // ---- layer 1 (BN+relu of h0 fused into A staging) ----
  k_gemm4<<<gg, 256, 0, stream>>>(out_b, wt1_l, wt1_r, bl + 128, br + 128,
                                  xs_b, xd_b,
                                  ssum0, ssq0, gm, bt,
                                  nullptr, nullptr, 2);
  k_edge3<<<(NN + 3) / 4, 256, 0, stream>>>(xs_b, xd_b, row_start, deg, srcs,
                                            att + 128, cb + 128, out_b);
  k_gemm4<<<gg, 256, 0, stream>>>(out_b, wt1_lin, nullptr, blin + 128, nullptr,
                                  out_b, nullptr,
                                  nullptr, nullptr, nullptr, nullptr,
                                  ssum1, ssq1, 1);
  k_bn<<<(NN * 64 + 255) / 256, 256, 0, stream>>>(out_b, ssum1, ssq1,
                                                  gm + 128, bt + 128, (float*)d_out);
}